// Round 3
// baseline (21295.686 us; speedup 1.0000x reference)
//
#include <hip/hip_runtime.h>
#include <stdint.h>

#define SEQ  2048
#define HID  2048
#define INP  1024
#define OUTW 512
#define SENT 0x7F7F7F7Fu   // 3.39e38f; |h|<1 so a real h word never matches

__device__ __forceinline__ unsigned short f2bf(float x){
  unsigned int u = __float_as_uint(x);
  u += 0x7fffu + ((u >> 16) & 1u);           // RNE
  return (unsigned short)(u >> 16);
}
__device__ __forceinline__ float bf_lo(unsigned int w){ return __uint_as_float(w << 16); }

// ---------------- Phase 0: sentinel-fill hist ----------------
__global__ __launch_bounds__(256)
void fill_hist(uint4* __restrict__ hist4){
  size_t i = (size_t)blockIdx.x*blockDim.x + threadIdx.x;   // 1,048,576 uint4 = 16 MB
  hist4[i] = make_uint4(SENT,SENT,SENT,SENT);
}

// ---------------- Phase A: Xproj[b][t][u][g] = W_g[j][2048:] @ x_t + b_g[j], bf16 ----------------
__global__ __launch_bounds__(256)
void xproj_gemm(const float* __restrict__ Wf, const float* __restrict__ Wi,
                const float* __restrict__ Wc, const float* __restrict__ Wo,
                const float* __restrict__ bfv, const float* __restrict__ biv,
                const float* __restrict__ bcv, const float* __restrict__ bov,
                const float* __restrict__ X, unsigned short* __restrict__ xproj)
{
  __shared__ float As[16][68];
  __shared__ float Bs[16][68];
  const int t0 = blockIdx.x * 64;
  const int r0 = blockIdx.y * 64;
  const int gate = r0 >> 11;
  const int j0 = r0 & 2047;
  const float* Wg = gate==0?Wf:gate==1?Wi:gate==2?Wc:Wo;
  const float* bg = gate==0?bfv:gate==1?biv:gate==2?bcv:bov;
  const int tid = threadIdx.x;
  const int tx = tid & 15, ty = tid >> 4;
  const int lr = tid >> 2;
  const int lk = (tid & 3) * 4;
  float acc[4][4] = {};
  for (int k0 = 0; k0 < INP; k0 += 16){
    float4 av = *(const float4*)(Wg + (size_t)(j0+lr)*3072 + 2048 + k0 + lk);
    float4 bv = *(const float4*)(X  + (size_t)(t0+lr)*INP  + k0 + lk);
    __syncthreads();
    As[lk+0][lr]=av.x; As[lk+1][lr]=av.y; As[lk+2][lr]=av.z; As[lk+3][lr]=av.w;
    Bs[lk+0][lr]=bv.x; Bs[lk+1][lr]=bv.y; Bs[lk+2][lr]=bv.z; Bs[lk+3][lr]=bv.w;
    __syncthreads();
    #pragma unroll
    for (int kk=0;kk<16;kk++){
      float a[4], bb[4];
      #pragma unroll
      for (int i=0;i<4;i++) a[i]  = As[kk][ty*4+i];
      #pragma unroll
      for (int j=0;j<4;j++) bb[j] = Bs[kk][tx*4+j];
      #pragma unroll
      for (int i=0;i<4;i++)
        #pragma unroll
        for (int j=0;j<4;j++)
          acc[i][j] = fmaf(a[i], bb[j], acc[i][j]);
    }
  }
  #pragma unroll
  for (int i=0;i<4;i++){
    int j = j0 + ty*4 + i;
    float bias = bg[j];
    int bb = j >> 3, u = j & 7;
    #pragma unroll
    for (int jj=0;jj<4;jj++){
      int t = t0 + tx*4 + jj;
      size_t idx = (((size_t)bb*SEQ + t)*8 + u)*4 + gate;   // [b][t][u][g]
      xproj[idx] = f2bf(acc[i][jj] + bias);
    }
  }
}

// ---------------- Phase B: register-direct barrier-free scan ----------------
// 256 blocks x 512 thr (8 waves), 1 block/CU. Wave w of block b owns hidden
// unit u = 8b+w, all 4 gate rows (4x2048 fp32) in 128 VGPR/lane.
// Protocol = R1's proven one (fp32 4-byte agent-relaxed publishes, pollers
// blocked on long-latency fabric loads), but each wave polls the FULL fp32 row
// h_{t-1} directly into the registers the dot consumes (lane slice
// 8*lane+512*kc+{0..7} is lane-contiguous): detect == operand load. No block
// barrier, no LDS exchange, no bf16 pack/unpack. The data dependency itself
// synchronizes waves; no shared state remains in the block.
__global__ __launch_bounds__(512, 1)
void lstm_scan_reg(const float* __restrict__ Wf, const float* __restrict__ Wi,
                   const float* __restrict__ Wc, const float* __restrict__ Wo,
                   const unsigned short* __restrict__ xproj,
                   float* __restrict__ hist)       // d_out hidden region [SEQ][HID]
{
  const int b    = blockIdx.x;
  const int tid  = threadIdx.x;
  const int wv   = tid >> 6;
  const int lane = tid & 63;
  const int u    = b*8 + wv;

  // fp32 weights: wreg[r][kc*8+j] = W_{gate r}[u][8*lane + 512*kc + j]
  const float* const Wm[4] = {Wf, Wi, Wc, Wo};
  float wreg[4][32];
  #pragma unroll
  for (int r=0;r<4;r++){
    const float* rowp = Wm[r] + (size_t)u*3072;
    #pragma unroll
    for (int kc=0;kc<4;kc++){
      float4 f0 = *(const float4*)(rowp + 8*lane + 512*kc);
      float4 f1 = *(const float4*)(rowp + 8*lane + 512*kc + 4);
      wreg[r][kc*8+0]=f0.x; wreg[r][kc*8+1]=f0.y; wreg[r][kc*8+2]=f0.z; wreg[r][kc*8+3]=f0.w;
      wreg[r][kc*8+4]=f1.x; wreg[r][kc*8+5]=f1.y; wreg[r][kc*8+6]=f1.z; wreg[r][kc*8+7]=f1.w;
    }
  }

  float c = 0.0f;
  const unsigned short* xpp = xproj + (size_t)b*SEQ*32 + wv*4 + lane; // lane<4 valid

  for (int t=0; t<SEQ; t++){
    // x-projection (tiny, cached) — issue before the h poll
    float xp = (lane < 4) ? bf_lo((unsigned)xpp[(size_t)t*32]) : 0.0f;

    // ---- acquire h_{t-1}: full row into regs, sentinel-validated ----
    // q[4*kc+j2] holds fp32 cols (8*lane + 512*kc + 2*j2, +1)
    unsigned long long q[16];
    if (t == 0){
      #pragma unroll
      for (int i=0;i<16;i++) q[i] = 0ULL;        // h_{-1} = 0
    } else {
      const unsigned long long* hq =
        (const unsigned long long*)(hist + (size_t)(t-1)*HID);
      #pragma unroll
      for (int kc=0;kc<4;kc++){
        const unsigned long long* p = hq + 4*lane + 256*kc;
        #pragma unroll
        for (int j2=0;j2<4;j2++)
          q[4*kc+j2] = __hip_atomic_load(p+j2, __ATOMIC_RELAXED, __HIP_MEMORY_SCOPE_AGENT);
      }
      int gd = 0;
      for(;;){
        bool st[16]; bool any = false;
        #pragma unroll
        for (int i=0;i<16;i++){
          st[i] = ((unsigned)q[i]==SENT) | ((unsigned)(q[i]>>32)==SENT);
          any |= st[i];
        }
        if (!any || gd >= (1<<17)) break;        // guard: fail wrong, never hang
        #pragma unroll
        for (int i=0;i<16;i++) if (st[i]){
          const unsigned long long* p = hq + 4*lane + 256*(i>>2) + (i&3);
          q[i] = __hip_atomic_load(p, __ATOMIC_RELAXED, __HIP_MEMORY_SCOPE_AGENT);
        }
        gd++;
      }
    }

    // ---- dot: 4 gate rows x 32 cols/lane, fp32 h, 2 partial accs/gate ----
    float p0[4] = {0.f,0.f,0.f,0.f};
    float p1[4] = {0.f,0.f,0.f,0.f};
    #pragma unroll
    for (int kc=0;kc<4;kc++){
      float h8[8];
      #pragma unroll
      for (int j2=0;j2<4;j2++){
        h8[2*j2]   = __uint_as_float((unsigned)q[4*kc+j2]);
        h8[2*j2+1] = __uint_as_float((unsigned)(q[4*kc+j2]>>32));
      }
      #pragma unroll
      for (int r=0;r<4;r++){
        #pragma unroll
        for (int j=0;j<4;j++) p0[r] = fmaf(wreg[r][kc*8+j],   h8[j],   p0[r]);
        #pragma unroll
        for (int j=0;j<4;j++) p1[r] = fmaf(wreg[r][kc*8+4+j], h8[4+j], p1[r]);
      }
    }
    float acc[4];
    #pragma unroll
    for (int r=0;r<4;r++) acc[r] = p0[r] + p1[r];

    // ---- pair-folding butterfly: lane l ends with gate (l&3) fully reduced ----
    const int b0 = lane & 1;
    const int b1 = lane & 2;
    float x01 = b0 ? acc[1] : acc[0];
    float y01 = b0 ? acc[0] : acc[1];
    x01 += __shfl_xor(y01, 1);
    float x23 = b0 ? acc[3] : acc[2];
    float y23 = b0 ? acc[2] : acc[3];
    x23 += __shfl_xor(y23, 1);
    float xk = b1 ? x23 : x01;
    float yk = b1 ? x01 : x23;
    xk += __shfl_xor(yk, 2);
    xk += __shfl_xor(xk, 4);
    xk += __shfl_xor(xk, 8);
    xk += __shfl_xor(xk, 16);
    xk += __shfl_xor(xk, 32);

    // ---- activations in-wave ----
    float pre = xk + __shfl(xp, lane & 3);
    const bool ist = ((lane & 3) == 2);        // gate 2 = tanh, others sigmoid
    float px = ist ? fminf(15.0f, fmaxf(-15.0f, pre)) : pre;
    float e  = __expf(ist ? -2.0f*px : -px);
    float d  = 1.0f/(1.0f + e);
    float gv = ist ? (1.0f - e)*d : d;

    float f  = __shfl(gv, 0);
    float ii = __shfl(gv, 1);
    float cg = __shfl(gv, 2);
    float o  = __shfl(gv, 3);

    c = fmaf(f, c, ii*cg);
    float cx = fminf(15.0f, fmaxf(-15.0f, c));
    float e2 = __expf(-2.0f*cx);
    float h  = o * (1.0f - e2)/(1.0f + e2);

    // ---- publish immediately (fire-and-forget, self-validating) ----
    if (lane == 0)
      __hip_atomic_store(hist + (size_t)t*HID + u, h,
                         __ATOMIC_RELAXED, __HIP_MEMORY_SCOPE_AGENT);
  }
}

// ---------------- Phase C: y[t][o] = W_y[o] @ h_t + b_y[o] ----------------
__global__ __launch_bounds__(256)
void ygemm(const float* __restrict__ hist, const float* __restrict__ Wy,
           const float* __restrict__ by, float* __restrict__ yout)
{
  __shared__ float As[16][68];
  __shared__ float Bs[16][68];
  const int o0 = blockIdx.x * 64;
  const int t0 = blockIdx.y * 64;
  const int tid = threadIdx.x;
  const int tx = tid & 15, ty = tid >> 4;
  const int lr = tid >> 2;
  const int lk = (tid & 3) * 4;
  float acc[4][4] = {};
  for (int k0 = 0; k0 < HID; k0 += 16){
    float4 av = *(const float4*)(hist + (size_t)(t0+lr)*HID + k0 + lk);
    float4 bv = *(const float4*)(Wy   + (size_t)(o0+lr)*HID + k0 + lk);
    __syncthreads();
    As[lk+0][lr]=av.x; As[lk+1][lr]=av.y; As[lk+2][lr]=av.z; As[lk+3][lr]=av.w;
    Bs[lk+0][lr]=bv.x; Bs[lk+1][lr]=bv.y; Bs[lk+2][lr]=bv.z; Bs[lk+3][lr]=bv.w;
    __syncthreads();
    #pragma unroll
    for (int kk=0;kk<16;kk++){
      float a[4], bb[4];
      #pragma unroll
      for (int i=0;i<4;i++) a[i]  = As[kk][ty*4+i];
      #pragma unroll
      for (int j=0;j<4;j++) bb[j] = Bs[kk][tx*4+j];
      #pragma unroll
      for (int i=0;i<4;i++)
        #pragma unroll
        for (int j=0;j<4;j++)
          acc[i][j] = fmaf(a[i], bb[j], acc[i][j]);
    }
  }
  #pragma unroll
  for (int i=0;i<4;i++){
    int t = t0 + ty*4 + i;
    #pragma unroll
    for (int jj=0;jj<4;jj++){
      int o = o0 + tx*4 + jj;
      yout[(size_t)t*OUTW + o] = acc[i][jj] + by[o];
    }
  }
}

extern "C" void kernel_launch(void* const* d_in, const int* in_sizes, int n_in,
                              void* d_out, int out_size, void* d_ws, size_t ws_size,
                              hipStream_t stream) {
  const float* X  = (const float*)d_in[0];
  const float* Wf = (const float*)d_in[1];
  const float* bf = (const float*)d_in[2];
  const float* Wi = (const float*)d_in[3];
  const float* bi = (const float*)d_in[4];
  const float* Wc = (const float*)d_in[5];
  const float* bc = (const float*)d_in[6];
  const float* Wo = (const float*)d_in[7];
  const float* bo = (const float*)d_in[8];
  const float* Wy = (const float*)d_in[9];
  const float* by = (const float*)d_in[10];

  float* yout = (float*)d_out;                       // [2048][512]
  float* hist = (float*)d_out + (size_t)SEQ*OUTW;    // [2048][2048]

  const size_t XPROJ_BYTES = (size_t)256*SEQ*32*sizeof(unsigned short); // 33,554,432
  if (ws_size < XPROJ_BYTES) return;   // clean failure instead of corruption

  unsigned short* xproj = (unsigned short*)d_ws;

  // sentinel-fill hist (16 MB); stream-ordered before the scan
  fill_hist<<<(SEQ*(size_t)HID/4)/256, 256, 0, stream>>>((uint4*)hist);

  dim3 gA(32, 128);
  xproj_gemm<<<gA, 256, 0, stream>>>(Wf,Wi,Wc,Wo, bf,bi,bc,bo, X, xproj);
  lstm_scan_reg<<<256, 512, 0, stream>>>(Wf,Wi,Wc,Wo, xproj, hist);
  dim3 gY(8, 32);
  ygemm<<<gY, 256, 0, stream>>>(hist, Wy, by, yout);
}

// Round 4
// 11174.532 us; speedup vs baseline: 1.9057x; 1.9057x over previous
//
#include <hip/hip_runtime.h>
#include <stdint.h>

#define SEQ  2048
#define HID  2048
#define INP  1024
#define OUTW 512
#define SENT 0x7F7F7F7Fu   // 3.39e38f; |h|<1 so a real h word never matches

__device__ __forceinline__ float bf_lo(unsigned int w){ return __uint_as_float(w << 16); }
__device__ __forceinline__ float bf_hi(unsigned int w){ return __uint_as_float(w & 0xffff0000u); }

// ---------------- Phase 0: sentinel-fill hist ----------------
__global__ __launch_bounds__(256)
void fill_hist(uint4* __restrict__ hist4){
  size_t i = (size_t)blockIdx.x*blockDim.x + threadIdx.x;   // 1,048,576 uint4 = 16 MB
  hist4[i] = make_uint4(SENT,SENT,SENT,SENT);
}

// ---------------- Fused persistent LSTM: scan + x-projection + y epilogue ----------------
// 256 blocks x 512 thr (8 waves). Wave w of block b owns hidden unit u = 8b+w,
// all 4 gate h-rows (4x2048 fp32) in 128 VGPR/lane.  EXCHANGE PROTOCOL = R1's
// proven one, verbatim: fp32 4-byte agent-relaxed publishes; every thread polls
// its own 16 B slice of h_{t-1}; truncate-pack to bf16 pairs into LDS
// (double-buffered by t&1); ONE __syncthreads per step; in-wave butterfly
// reduce + activations; lane 0 publishes immediately.
//
// New vs R1 (both OFF the sync protocol):
//  * x-projection fused: W_g[u][2048+16*lane .. +15] and X[t][16*lane ..] are
//    h-independent; their plain loads issue BEFORE the poll (latency hides
//    under the spin RTT), xpart[4] computes in the ds_read shadow after the
//    barrier, and seeds the butterfly accumulators. xproj_gemm kernel deleted.
//  * y epilogue fused: after the loop, poll-validate row SEQ-1 (its
//    completeness implies all rows complete), then each block computes one
//    64x64 y-tile with the proven ygemm body (tid<256, uniform barriers).
__global__ __launch_bounds__(512, 2)
void lstm_fused(const float* __restrict__ Wf, const float* __restrict__ Wi,
                const float* __restrict__ Wc, const float* __restrict__ Wo,
                const float* __restrict__ bfv, const float* __restrict__ biv,
                const float* __restrict__ bcv, const float* __restrict__ bov,
                const float* __restrict__ X,  const float* __restrict__ Wy,
                const float* __restrict__ byv,
                float* __restrict__ hist,      // d_out hidden region [SEQ][HID]
                float* __restrict__ yout)      // d_out y region [SEQ][OUTW]
{
  const int b    = blockIdx.x;
  const int tid  = threadIdx.x;
  const int wv   = tid >> 6;
  const int lane = tid & 63;
  const int u    = b*8 + wv;

  __shared__ unsigned int h_lds[2][HID/2];  // packed bf16 pairs: word W = cols (2W,2W+1)
  __shared__ float As[16][68];              // epilogue staging
  __shared__ float Bs[16][68];

  // fp32 h-weights: wreg[r][kc*8+j] = W_{gate r}[u][8*lane + 512*kc + j]
  const float* const Wm[4] = {Wf, Wi, Wc, Wo};
  float wreg[4][32];
  #pragma unroll
  for (int r=0;r<4;r++){
    const float* rowp = Wm[r] + (size_t)u*3072;
    #pragma unroll
    for (int kc=0;kc<4;kc++){
      float4 f0 = *(const float4*)(rowp + 8*lane + 512*kc);
      float4 f1 = *(const float4*)(rowp + 8*lane + 512*kc + 4);
      wreg[r][kc*8+0]=f0.x; wreg[r][kc*8+1]=f0.y; wreg[r][kc*8+2]=f0.z; wreg[r][kc*8+3]=f0.w;
      wreg[r][kc*8+4]=f1.x; wreg[r][kc*8+5]=f1.y; wreg[r][kc*8+6]=f1.z; wreg[r][kc*8+7]=f1.w;
    }
  }

  // bias for this lane's gate (lane&3) of unit u
  float bias_sel;
  {
    float b0=bfv[u], b1=biv[u], b2=bcv[u], b3=bov[u];
    int gg = lane & 3;
    bias_sel = (gg==0) ? b0 : (gg==1) ? b1 : (gg==2) ? b2 : b3;
  }

  // x-side base pointers (per-lane 16-col slice of the x-part of each gate row)
  const float* wxb0 = Wf + (size_t)u*3072 + 2048 + 16*lane;
  const float* wxb1 = Wi + (size_t)u*3072 + 2048 + 16*lane;
  const float* wxb2 = Wc + (size_t)u*3072 + 2048 + 16*lane;
  const float* wxb3 = Wo + (size_t)u*3072 + 2048 + 16*lane;
  const float* xb   = X + 16*lane;

  float c = 0.0f;

  for (int t=0; t<SEQ; t++){
    // ---- issue h-independent loads first: X[t] slice + 4 gate W-x slices ----
    const float* xr = xb + (size_t)t*INP;
    float4 xv0 = *(const float4*)(xr+0),  xv1 = *(const float4*)(xr+4);
    float4 xv2 = *(const float4*)(xr+8),  xv3 = *(const float4*)(xr+12);
    float4 w0a = *(const float4*)(wxb0+0), w0b = *(const float4*)(wxb0+4),
           w0c = *(const float4*)(wxb0+8), w0d = *(const float4*)(wxb0+12);
    float4 w1a = *(const float4*)(wxb1+0), w1b = *(const float4*)(wxb1+4),
           w1c = *(const float4*)(wxb1+8), w1d = *(const float4*)(wxb1+12);
    float4 w2a = *(const float4*)(wxb2+0), w2b = *(const float4*)(wxb2+4),
           w2c = *(const float4*)(wxb2+8), w2d = *(const float4*)(wxb2+12);
    float4 w3a = *(const float4*)(wxb3+0), w3b = *(const float4*)(wxb3+4),
           w3c = *(const float4*)(wxb3+8), w3d = *(const float4*)(wxb3+12);

    // ---- acquire h_{t-1}: R1's sentinel poll, verbatim ----
    uint2 pk;
    if (t == 0){
      pk.x = 0u; pk.y = 0u;                  // h_{-1} = 0 (bf16 zeros)
    } else {
      const unsigned long long* hp =
        (const unsigned long long*)(hist + (size_t)(t-1)*HID) + 2*tid;  // floats 4tid..4tid+3
      unsigned long long qa = __hip_atomic_load(hp,   __ATOMIC_RELAXED, __HIP_MEMORY_SCOPE_AGENT);
      unsigned long long qb = __hip_atomic_load(hp+1, __ATOMIC_RELAXED, __HIP_MEMORY_SCOPE_AGENT);
      int gd = 0;
      for(;;){
        bool ba = ((unsigned)qa==SENT) | ((unsigned)(qa>>32)==SENT);
        bool bb = ((unsigned)qb==SENT) | ((unsigned)(qb>>32)==SENT);
        if (!(ba|bb) || gd >= (1<<17)) break;   // guard: fail wrong, never hang
        if (ba) qa = __hip_atomic_load(hp,   __ATOMIC_RELAXED, __HIP_MEMORY_SCOPE_AGENT);
        if (bb) qb = __hip_atomic_load(hp+1, __ATOMIC_RELAXED, __HIP_MEMORY_SCOPE_AGENT);
        gd++;
      }
      unsigned a0=(unsigned)qa, a1=(unsigned)(qa>>32), a2=(unsigned)qb, a3=(unsigned)(qb>>32);
      pk.x = (a1 & 0xffff0000u) | (a0 >> 16);   // truncate-pack to bf16 pairs
      pk.y = (a3 & 0xffff0000u) | (a2 >> 16);
    }
    const int p = t & 1;
    *(uint2*)&h_lds[p][2*tid] = pk;
    __syncthreads();                          // the ONLY barrier per step

    // ---- x-projection partials (fills the ds_read latency shadow) ----
    float xpart[4];
    {
      xpart[0] = w0a.x*xv0.x + w0a.y*xv0.y + w0a.z*xv0.z + w0a.w*xv0.w
               + w0b.x*xv1.x + w0b.y*xv1.y + w0b.z*xv1.z + w0b.w*xv1.w
               + w0c.x*xv2.x + w0c.y*xv2.y + w0c.z*xv2.z + w0c.w*xv2.w
               + w0d.x*xv3.x + w0d.y*xv3.y + w0d.z*xv3.z + w0d.w*xv3.w;
      xpart[1] = w1a.x*xv0.x + w1a.y*xv0.y + w1a.z*xv0.z + w1a.w*xv0.w
               + w1b.x*xv1.x + w1b.y*xv1.y + w1b.z*xv1.z + w1b.w*xv1.w
               + w1c.x*xv2.x + w1c.y*xv2.y + w1c.z*xv2.z + w1c.w*xv2.w
               + w1d.x*xv3.x + w1d.y*xv3.y + w1d.z*xv3.z + w1d.w*xv3.w;
      xpart[2] = w2a.x*xv0.x + w2a.y*xv0.y + w2a.z*xv0.z + w2a.w*xv0.w
               + w2b.x*xv1.x + w2b.y*xv1.y + w2b.z*xv1.z + w2b.w*xv1.w
               + w2c.x*xv2.x + w2c.y*xv2.y + w2c.z*xv2.z + w2c.w*xv2.w
               + w2d.x*xv3.x + w2d.y*xv3.y + w2d.z*xv3.z + w2d.w*xv3.w;
      xpart[3] = w3a.x*xv0.x + w3a.y*xv0.y + w3a.z*xv0.z + w3a.w*xv0.w
               + w3b.x*xv1.x + w3b.y*xv1.y + w3b.z*xv1.z + w3b.w*xv1.w
               + w3c.x*xv2.x + w3c.y*xv2.y + w3c.z*xv2.z + w3c.w*xv2.w
               + w3d.x*xv3.x + w3d.y*xv3.y + w3d.z*xv3.z + w3d.w*xv3.w;
    }

    // ---- dot: 4 gate rows x 32 cols/lane (R1 verbatim, seeded with xpart) ----
    float acc[4] = {xpart[0], xpart[1], xpart[2], xpart[3]};
    #pragma unroll
    for (int kc=0;kc<4;kc++){
      uint4 hw = *(const uint4*)&h_lds[p][4*lane + 256*kc];   // cols 8*lane+512*kc+0..7
      float hf[8];
      hf[0]=bf_lo(hw.x); hf[1]=bf_hi(hw.x); hf[2]=bf_lo(hw.y); hf[3]=bf_hi(hw.y);
      hf[4]=bf_lo(hw.z); hf[5]=bf_hi(hw.z); hf[6]=bf_lo(hw.w); hf[7]=bf_hi(hw.w);
      #pragma unroll
      for (int r=0;r<4;r++)
        #pragma unroll
        for (int j=0;j<8;j++)
          acc[r] = fmaf(wreg[r][kc*8+j], hf[j], acc[r]);
    }

    // ---- pair-folding butterfly: lane l ends with gate (l&3) fully reduced ----
    const int b0 = lane & 1;
    const int b1 = lane & 2;
    float x01 = b0 ? acc[1] : acc[0];
    float y01 = b0 ? acc[0] : acc[1];
    x01 += __shfl_xor(y01, 1);
    float x23 = b0 ? acc[3] : acc[2];
    float y23 = b0 ? acc[2] : acc[3];
    x23 += __shfl_xor(y23, 1);
    float xk = b1 ? x23 : x01;
    float yk = b1 ? x01 : x23;
    xk += __shfl_xor(yk, 2);
    xk += __shfl_xor(xk, 4);
    xk += __shfl_xor(xk, 8);
    xk += __shfl_xor(xk, 16);
    xk += __shfl_xor(xk, 32);

    // ---- activations in-wave ----
    float pre = xk + bias_sel;
    const bool ist = ((lane & 3) == 2);        // gate 2 = tanh, others sigmoid
    float px = ist ? fminf(15.0f, fmaxf(-15.0f, pre)) : pre;
    float e  = __expf(ist ? -2.0f*px : -px);
    float d  = 1.0f/(1.0f + e);
    float gv = ist ? (1.0f - e)*d : d;

    float f  = __shfl(gv, 0);
    float ii = __shfl(gv, 1);
    float cg = __shfl(gv, 2);
    float o  = __shfl(gv, 3);

    c = fmaf(f, c, ii*cg);
    float cx = fminf(15.0f, fmaxf(-15.0f, c));
    float e2 = __expf(-2.0f*cx);
    float h  = o * (1.0f - e2)/(1.0f + e2);

    // ---- publish immediately (fire-and-forget, self-validating) ----
    if (lane == 0)
      __hip_atomic_store(hist + (size_t)t*HID + u, h,
                         __ATOMIC_RELAXED, __HIP_MEMORY_SCOPE_AGENT);
  }

  // ================= epilogue: y[t][o] = W_y[o] @ h_t + b_y[o] =================
  // Row SEQ-1 complete => all rows complete (h_t required full h_{t-1}).
  {
    const unsigned long long* hp =
      (const unsigned long long*)(hist + (size_t)(SEQ-1)*HID) + 2*tid;
    unsigned long long qa = __hip_atomic_load(hp,   __ATOMIC_RELAXED, __HIP_MEMORY_SCOPE_AGENT);
    unsigned long long qb = __hip_atomic_load(hp+1, __ATOMIC_RELAXED, __HIP_MEMORY_SCOPE_AGENT);
    int gd = 0;
    for(;;){
      bool ba = ((unsigned)qa==SENT) | ((unsigned)(qa>>32)==SENT);
      bool bb = ((unsigned)qb==SENT) | ((unsigned)(qb>>32)==SENT);
      if (!(ba|bb) || gd >= (1<<17)) break;
      if (ba) qa = __hip_atomic_load(hp,   __ATOMIC_RELAXED, __HIP_MEMORY_SCOPE_AGENT);
      if (bb) qb = __hip_atomic_load(hp+1, __ATOMIC_RELAXED, __HIP_MEMORY_SCOPE_AGENT);
      gd++;
    }
  }
  __syncthreads();

  // one 64x64 tile per block; tid<256 computes (proven ygemm body), barriers uniform
  const int t0 = (b >> 3) * 64;
  const int o0 = (b & 7) * 64;
  const int tx = tid & 15, ty = (tid >> 4) & 15;
  const int lr = (tid & 255) >> 2;
  const int lk = (tid & 3) * 4;
  float yacc[4][4] = {};
  for (int k0 = 0; k0 < HID; k0 += 16){
    if (tid < 256){
      float4 av = *(const float4*)(hist + (size_t)(t0+lr)*HID + k0 + lk);
      float4 bv = *(const float4*)(Wy   + (size_t)(o0+lr)*HID + k0 + lk);
      As[lk+0][lr]=av.x; As[lk+1][lr]=av.y; As[lk+2][lr]=av.z; As[lk+3][lr]=av.w;
      Bs[lk+0][lr]=bv.x; Bs[lk+1][lr]=bv.y; Bs[lk+2][lr]=bv.z; Bs[lk+3][lr]=bv.w;
    }
    __syncthreads();
    if (tid < 256){
      #pragma unroll
      for (int kk=0;kk<16;kk++){
        float a[4], bb2[4];
        #pragma unroll
        for (int i=0;i<4;i++) a[i]   = As[kk][ty*4+i];
        #pragma unroll
        for (int j=0;j<4;j++) bb2[j] = Bs[kk][tx*4+j];
        #pragma unroll
        for (int i=0;i<4;i++)
          #pragma unroll
          for (int j=0;j<4;j++)
            yacc[i][j] = fmaf(a[i], bb2[j], yacc[i][j]);
      }
    }
    __syncthreads();
  }
  if (tid < 256){
    #pragma unroll
    for (int i=0;i<4;i++){
      int t = t0 + ty*4 + i;
      #pragma unroll
      for (int jj=0;jj<4;jj++){
        int o = o0 + tx*4 + jj;
        yout[(size_t)t*OUTW + o] = yacc[i][jj] + byv[o];
      }
    }
  }
}

extern "C" void kernel_launch(void* const* d_in, const int* in_sizes, int n_in,
                              void* d_out, int out_size, void* d_ws, size_t ws_size,
                              hipStream_t stream) {
  const float* X  = (const float*)d_in[0];
  const float* Wf = (const float*)d_in[1];
  const float* bf = (const float*)d_in[2];
  const float* Wi = (const float*)d_in[3];
  const float* bi = (const float*)d_in[4];
  const float* Wc = (const float*)d_in[5];
  const float* bc = (const float*)d_in[6];
  const float* Wo = (const float*)d_in[7];
  const float* bo = (const float*)d_in[8];
  const float* Wy = (const float*)d_in[9];
  const float* by = (const float*)d_in[10];

  float* yout = (float*)d_out;                       // [2048][512]
  float* hist = (float*)d_out + (size_t)SEQ*OUTW;    // [2048][2048]

  // sentinel-fill hist (16 MB); stream-ordered before the scan
  fill_hist<<<(SEQ*(size_t)HID/4)/256, 256, 0, stream>>>((uint4*)hist);

  lstm_fused<<<256, 512, 0, stream>>>(Wf,Wi,Wc,Wo, bf,bi,bc,bo,
                                      X, Wy, by, hist, yout);
}

// Round 5
// 11073.965 us; speedup vs baseline: 1.9230x; 1.0091x over previous
//
#include <hip/hip_runtime.h>
#include <stdint.h>

#define SEQ  2048
#define HID  2048
#define INP  1024
#define OUTW 512
#define SENT 0x7F7F7F7Fu   // 3.39e38f; |h|<1 so a real h word never matches

__device__ __forceinline__ float bf_lo(unsigned int w){ return __uint_as_float(w << 16); }
__device__ __forceinline__ float bf_hi(unsigned int w){ return __uint_as_float(w & 0xffff0000u); }

// ---------------- Phase 0: sentinel-fill hist ----------------
__global__ __launch_bounds__(256)
void fill_hist(uint4* __restrict__ hist4){
  size_t i = (size_t)blockIdx.x*blockDim.x + threadIdx.x;   // 1,048,576 uint4 = 16 MB
  hist4[i] = make_uint4(SENT,SENT,SENT,SENT);
}

// ---------------- Fused persistent LSTM: scan + x-projection + y epilogue ----------------
// 256 blocks x 512 thr (8 waves), exactly 1 block/CU (grid == CU count).
// Wave w of block b owns hidden unit u = 8b+w:
//   - 4 gate h-rows (4x2048 fp32) in 128 VGPR/lane   (wreg)
//   - 4 gate x-rows' lane slice (4x16 fp32) in 64 VGPR/lane (wx)  <- HOISTED:
//     this was R4's mistake — reloading these per step cost 128 KB/block/step
//     of LLC fetch and saturated the fabric (FETCH_SIZE 512 MB, 2.7x slowdown).
// EXCHANGE PROTOCOL = R1's proven one, verbatim: fp32 4-byte agent-relaxed
// publishes; every thread polls its own 16 B slice of h_{t-1};
// truncate-pack to bf16 pairs into LDS (double-buffered by t&1); ONE
// __syncthreads per step; in-wave butterfly reduce + activations; lane 0
// publishes immediately. Per-step fabric traffic: 8 KB poll + 4 KB X row.
__global__ __launch_bounds__(512, 1)
void lstm_fused(const float* __restrict__ Wf, const float* __restrict__ Wi,
                const float* __restrict__ Wc, const float* __restrict__ Wo,
                const float* __restrict__ bfv, const float* __restrict__ biv,
                const float* __restrict__ bcv, const float* __restrict__ bov,
                const float* __restrict__ X,  const float* __restrict__ Wy,
                const float* __restrict__ byv,
                float* __restrict__ hist,      // d_out hidden region [SEQ][HID]
                float* __restrict__ yout)      // d_out y region [SEQ][OUTW]
{
  const int b    = blockIdx.x;
  const int tid  = threadIdx.x;
  const int wv   = tid >> 6;
  const int lane = tid & 63;
  const int u    = b*8 + wv;

  __shared__ unsigned int h_lds[2][HID/2];  // packed bf16 pairs: word W = cols (2W,2W+1)
  __shared__ float As[16][68];              // epilogue staging
  __shared__ float Bs[16][68];

  // fp32 h-weights: wreg[r][kc*8+j] = W_{gate r}[u][8*lane + 512*kc + j]
  const float* const Wm[4] = {Wf, Wi, Wc, Wo};
  float wreg[4][32];
  #pragma unroll
  for (int r=0;r<4;r++){
    const float* rowp = Wm[r] + (size_t)u*3072;
    #pragma unroll
    for (int kc=0;kc<4;kc++){
      float4 f0 = *(const float4*)(rowp + 8*lane + 512*kc);
      float4 f1 = *(const float4*)(rowp + 8*lane + 512*kc + 4);
      wreg[r][kc*8+0]=f0.x; wreg[r][kc*8+1]=f0.y; wreg[r][kc*8+2]=f0.z; wreg[r][kc*8+3]=f0.w;
      wreg[r][kc*8+4]=f1.x; wreg[r][kc*8+5]=f1.y; wreg[r][kc*8+6]=f1.z; wreg[r][kc*8+7]=f1.w;
    }
  }

  // fp32 x-weights, HOISTED (loop-invariant): wx[r][j] = W_{gate r}[u][2048 + 16*lane + j]
  float wx[4][16];
  #pragma unroll
  for (int r=0;r<4;r++){
    const float* rowp = Wm[r] + (size_t)u*3072 + 2048 + 16*lane;
    #pragma unroll
    for (int j4=0;j4<4;j4++){
      float4 f = *(const float4*)(rowp + 4*j4);
      wx[r][4*j4+0]=f.x; wx[r][4*j4+1]=f.y; wx[r][4*j4+2]=f.z; wx[r][4*j4+3]=f.w;
    }
  }

  // bias for this lane's gate (lane&3) of unit u
  float bias_sel;
  {
    float b0=bfv[u], b1=biv[u], b2=bcv[u], b3=bov[u];
    int gg = lane & 3;
    bias_sel = (gg==0) ? b0 : (gg==1) ? b1 : (gg==2) ? b2 : b3;
  }

  const float* xb = X + 16*lane;
  float c = 0.0f;

  for (int t=0; t<SEQ; t++){
    // ---- issue the only h-independent load: X[t] lane slice (64 B/lane) ----
    const float* xr = xb + (size_t)t*INP;
    float4 xv0 = *(const float4*)(xr+0),  xv1 = *(const float4*)(xr+4);
    float4 xv2 = *(const float4*)(xr+8),  xv3 = *(const float4*)(xr+12);

    // ---- acquire h_{t-1}: R1's sentinel poll, verbatim ----
    uint2 pk;
    if (t == 0){
      pk.x = 0u; pk.y = 0u;                  // h_{-1} = 0 (bf16 zeros)
    } else {
      const unsigned long long* hp =
        (const unsigned long long*)(hist + (size_t)(t-1)*HID) + 2*tid;  // floats 4tid..4tid+3
      unsigned long long qa = __hip_atomic_load(hp,   __ATOMIC_RELAXED, __HIP_MEMORY_SCOPE_AGENT);
      unsigned long long qb = __hip_atomic_load(hp+1, __ATOMIC_RELAXED, __HIP_MEMORY_SCOPE_AGENT);
      int gd = 0;
      for(;;){
        bool ba = ((unsigned)qa==SENT) | ((unsigned)(qa>>32)==SENT);
        bool bb = ((unsigned)qb==SENT) | ((unsigned)(qb>>32)==SENT);
        if (!(ba|bb) || gd >= (1<<17)) break;   // guard: fail wrong, never hang
        if (ba) qa = __hip_atomic_load(hp,   __ATOMIC_RELAXED, __HIP_MEMORY_SCOPE_AGENT);
        if (bb) qb = __hip_atomic_load(hp+1, __ATOMIC_RELAXED, __HIP_MEMORY_SCOPE_AGENT);
        gd++;
      }
      unsigned a0=(unsigned)qa, a1=(unsigned)(qa>>32), a2=(unsigned)qb, a3=(unsigned)(qb>>32);
      pk.x = (a1 & 0xffff0000u) | (a0 >> 16);   // truncate-pack to bf16 pairs
      pk.y = (a3 & 0xffff0000u) | (a2 >> 16);
    }
    const int p = t & 1;
    *(uint2*)&h_lds[p][2*tid] = pk;
    __syncthreads();                          // the ONLY barrier per step

    // ---- x-projection partials from REGISTER weights (ds_read latency shadow) ----
    float xpart[4];
    #pragma unroll
    for (int r=0;r<4;r++){
      float s0 = wx[r][0]*xv0.x + wx[r][1]*xv0.y + wx[r][2]*xv0.z + wx[r][3]*xv0.w;
      float s1 = wx[r][4]*xv1.x + wx[r][5]*xv1.y + wx[r][6]*xv1.z + wx[r][7]*xv1.w;
      float s2 = wx[r][8]*xv2.x + wx[r][9]*xv2.y + wx[r][10]*xv2.z + wx[r][11]*xv2.w;
      float s3 = wx[r][12]*xv3.x + wx[r][13]*xv3.y + wx[r][14]*xv3.z + wx[r][15]*xv3.w;
      xpart[r] = (s0 + s1) + (s2 + s3);
    }

    // ---- dot: 4 gate rows x 32 cols/lane (R1 verbatim, seeded with xpart) ----
    float acc[4] = {xpart[0], xpart[1], xpart[2], xpart[3]};
    #pragma unroll
    for (int kc=0;kc<4;kc++){
      uint4 hw = *(const uint4*)&h_lds[p][4*lane + 256*kc];   // cols 8*lane+512*kc+0..7
      float hf[8];
      hf[0]=bf_lo(hw.x); hf[1]=bf_hi(hw.x); hf[2]=bf_lo(hw.y); hf[3]=bf_hi(hw.y);
      hf[4]=bf_lo(hw.z); hf[5]=bf_hi(hw.z); hf[6]=bf_lo(hw.w); hf[7]=bf_hi(hw.w);
      #pragma unroll
      for (int r=0;r<4;r++)
        #pragma unroll
        for (int j=0;j<8;j++)
          acc[r] = fmaf(wreg[r][kc*8+j], hf[j], acc[r]);
    }

    // ---- pair-folding butterfly: lane l ends with gate (l&3) fully reduced ----
    const int b0 = lane & 1;
    const int b1 = lane & 2;
    float x01 = b0 ? acc[1] : acc[0];
    float y01 = b0 ? acc[0] : acc[1];
    x01 += __shfl_xor(y01, 1);
    float x23 = b0 ? acc[3] : acc[2];
    float y23 = b0 ? acc[2] : acc[3];
    x23 += __shfl_xor(y23, 1);
    float xk = b1 ? x23 : x01;
    float yk = b1 ? x01 : x23;
    xk += __shfl_xor(yk, 2);
    xk += __shfl_xor(xk, 4);
    xk += __shfl_xor(xk, 8);
    xk += __shfl_xor(xk, 16);
    xk += __shfl_xor(xk, 32);

    // ---- activations in-wave ----
    float pre = xk + bias_sel;
    const bool ist = ((lane & 3) == 2);        // gate 2 = tanh, others sigmoid
    float px = ist ? fminf(15.0f, fmaxf(-15.0f, pre)) : pre;
    float e  = __expf(ist ? -2.0f*px : -px);
    float d  = 1.0f/(1.0f + e);
    float gv = ist ? (1.0f - e)*d : d;

    float f  = __shfl(gv, 0);
    float ii = __shfl(gv, 1);
    float cg = __shfl(gv, 2);
    float o  = __shfl(gv, 3);

    c = fmaf(f, c, ii*cg);
    float cx = fminf(15.0f, fmaxf(-15.0f, c));
    float e2 = __expf(-2.0f*cx);
    float h  = o * (1.0f - e2)/(1.0f + e2);

    // ---- publish immediately (fire-and-forget, self-validating) ----
    if (lane == 0)
      __hip_atomic_store(hist + (size_t)t*HID + u, h,
                         __ATOMIC_RELAXED, __HIP_MEMORY_SCOPE_AGENT);
  }

  // ================= epilogue: y[t][o] = W_y[o] @ h_t + b_y[o] =================
  // Row SEQ-1 complete => all rows complete (h_t required full h_{t-1}).
  {
    const unsigned long long* hp =
      (const unsigned long long*)(hist + (size_t)(SEQ-1)*HID) + 2*tid;
    unsigned long long qa = __hip_atomic_load(hp,   __ATOMIC_RELAXED, __HIP_MEMORY_SCOPE_AGENT);
    unsigned long long qb = __hip_atomic_load(hp+1, __ATOMIC_RELAXED, __HIP_MEMORY_SCOPE_AGENT);
    int gd = 0;
    for(;;){
      bool ba = ((unsigned)qa==SENT) | ((unsigned)(qa>>32)==SENT);
      bool bb = ((unsigned)qb==SENT) | ((unsigned)(qb>>32)==SENT);
      if (!(ba|bb) || gd >= (1<<17)) break;
      if (ba) qa = __hip_atomic_load(hp,   __ATOMIC_RELAXED, __HIP_MEMORY_SCOPE_AGENT);
      if (bb) qb = __hip_atomic_load(hp+1, __ATOMIC_RELAXED, __HIP_MEMORY_SCOPE_AGENT);
      gd++;
    }
  }
  __syncthreads();

  // one 64x64 tile per block; tid<256 computes (proven ygemm body), barriers uniform
  const int t0 = (b >> 3) * 64;
  const int o0 = (b & 7) * 64;
  const int tx = tid & 15, ty = (tid >> 4) & 15;
  const int lr = (tid & 255) >> 2;
  const int lk = (tid & 3) * 4;
  float yacc[4][4] = {};
  for (int k0 = 0; k0 < HID; k0 += 16){
    if (tid < 256){
      float4 av = *(const float4*)(hist + (size_t)(t0+lr)*HID + k0 + lk);
      float4 bv = *(const float4*)(Wy   + (size_t)(o0+lr)*HID + k0 + lk);
      As[lk+0][lr]=av.x; As[lk+1][lr]=av.y; As[lk+2][lr]=av.z; As[lk+3][lr]=av.w;
      Bs[lk+0][lr]=bv.x; Bs[lk+1][lr]=bv.y; Bs[lk+2][lr]=bv.z; Bs[lk+3][lr]=bv.w;
    }
    __syncthreads();
    if (tid < 256){
      #pragma unroll
      for (int kk=0;kk<16;kk++){
        float a[4], bb2[4];
        #pragma unroll
        for (int i=0;i<4;i++) a[i]   = As[kk][ty*4+i];
        #pragma unroll
        for (int j=0;j<4;j++) bb2[j] = Bs[kk][tx*4+j];
        #pragma unroll
        for (int i=0;i<4;i++)
          #pragma unroll
          for (int j=0;j<4;j++)
            yacc[i][j] = fmaf(a[i], bb2[j], yacc[i][j]);
      }
    }
    __syncthreads();
  }
  if (tid < 256){
    #pragma unroll
    for (int i=0;i<4;i++){
      int t = t0 + ty*4 + i;
      #pragma unroll
      for (int jj=0;jj<4;jj++){
        int o = o0 + tx*4 + jj;
        yout[(size_t)t*OUTW + o] = yacc[i][jj] + byv[o];
      }
    }
  }
}

extern "C" void kernel_launch(void* const* d_in, const int* in_sizes, int n_in,
                              void* d_out, int out_size, void* d_ws, size_t ws_size,
                              hipStream_t stream) {
  const float* X  = (const float*)d_in[0];
  const float* Wf = (const float*)d_in[1];
  const float* bf = (const float*)d_in[2];
  const float* Wi = (const float*)d_in[3];
  const float* bi = (const float*)d_in[4];
  const float* Wc = (const float*)d_in[5];
  const float* bc = (const float*)d_in[6];
  const float* Wo = (const float*)d_in[7];
  const float* bo = (const float*)d_in[8];
  const float* Wy = (const float*)d_in[9];
  const float* by = (const float*)d_in[10];

  float* yout = (float*)d_out;                       // [2048][512]
  float* hist = (float*)d_out + (size_t)SEQ*OUTW;    // [2048][2048]

  // sentinel-fill hist (16 MB); stream-ordered before the scan
  fill_hist<<<(SEQ*(size_t)HID/4)/256, 256, 0, stream>>>((uint4*)hist);

  lstm_fused<<<256, 512, 0, stream>>>(Wf,Wi,Wc,Wo, bf,bi,bc,bo,
                                      X, Wy, by, hist, yout);
}

// Round 6
// 5284.137 us; speedup vs baseline: 4.0301x; 2.0957x over previous
//
#include <hip/hip_runtime.h>
#include <stdint.h>

#define SEQ  2048
#define HID  2048
#define INP  1024
#define OUTW 512
#define SENT 0x7F7F7F7Fu   // 3.39e38f; |h|<1 so a real h word never matches

__device__ __forceinline__ unsigned short f2bf(float x){
  unsigned int u = __float_as_uint(x);
  u += 0x7fffu + ((u >> 16) & 1u);           // RNE
  return (unsigned short)(u >> 16);
}
__device__ __forceinline__ float bf_lo(unsigned int w){ return __uint_as_float(w << 16); }
__device__ __forceinline__ float bf_hi(unsigned int w){ return __uint_as_float(w & 0xffff0000u); }

// ---------------- Phase 0: sentinel-fill hist ----------------
__global__ __launch_bounds__(256)
void fill_hist(uint4* __restrict__ hist4){
  size_t i = (size_t)blockIdx.x*blockDim.x + threadIdx.x;   // 1,048,576 uint4 = 16 MB
  hist4[i] = make_uint4(SENT,SENT,SENT,SENT);
}

// ---------------- Phase A: Xproj[b][t][u][g] = W_g[j][2048:] @ x_t + b_g[j], bf16 ----------------
__global__ __launch_bounds__(256)
void xproj_gemm(const float* __restrict__ Wf, const float* __restrict__ Wi,
                const float* __restrict__ Wc, const float* __restrict__ Wo,
                const float* __restrict__ bfv, const float* __restrict__ biv,
                const float* __restrict__ bcv, const float* __restrict__ bov,
                const float* __restrict__ X, unsigned short* __restrict__ xproj)
{
  __shared__ float As[16][68];
  __shared__ float Bs[16][68];
  const int t0 = blockIdx.x * 64;
  const int r0 = blockIdx.y * 64;
  const int gate = r0 >> 11;
  const int j0 = r0 & 2047;
  const float* Wg = gate==0?Wf:gate==1?Wi:gate==2?Wc:Wo;
  const float* bg = gate==0?bfv:gate==1?biv:gate==2?bcv:bov;
  const int tid = threadIdx.x;
  const int tx = tid & 15, ty = tid >> 4;
  const int lr = tid >> 2;
  const int lk = (tid & 3) * 4;
  float acc[4][4] = {};
  for (int k0 = 0; k0 < INP; k0 += 16){
    float4 av = *(const float4*)(Wg + (size_t)(j0+lr)*3072 + 2048 + k0 + lk);
    float4 bv = *(const float4*)(X  + (size_t)(t0+lr)*INP  + k0 + lk);
    __syncthreads();
    As[lk+0][lr]=av.x; As[lk+1][lr]=av.y; As[lk+2][lr]=av.z; As[lk+3][lr]=av.w;
    Bs[lk+0][lr]=bv.x; Bs[lk+1][lr]=bv.y; Bs[lk+2][lr]=bv.z; Bs[lk+3][lr]=bv.w;
    __syncthreads();
    #pragma unroll
    for (int kk=0;kk<16;kk++){
      float a[4], bb[4];
      #pragma unroll
      for (int i=0;i<4;i++) a[i]  = As[kk][ty*4+i];
      #pragma unroll
      for (int j=0;j<4;j++) bb[j] = Bs[kk][tx*4+j];
      #pragma unroll
      for (int i=0;i<4;i++)
        #pragma unroll
        for (int j=0;j<4;j++)
          acc[i][j] = fmaf(a[i], bb[j], acc[i][j]);
    }
  }
  #pragma unroll
  for (int i=0;i<4;i++){
    int j = j0 + ty*4 + i;
    float bias = bg[j];
    int bb = j >> 3, u = j & 7;
    #pragma unroll
    for (int jj=0;jj<4;jj++){
      int t = t0 + tx*4 + jj;
      size_t idx = (((size_t)bb*SEQ + t)*8 + u)*4 + gate;   // [b][t][u][g]
      xproj[idx] = f2bf(acc[i][jj] + bias);
    }
  }
}

// ---------------- Phase B: persistent recurrent scan (R1 protocol) + y epilogue ----------------
// 256 blocks x 512 thr (8 waves), 1 block/CU. Wave w of block b owns hidden
// unit u = 8b+w, all 4 gate h-rows (4x2048 fp32) in 128 VGPR/lane.
//
// KEY FIX vs R1: the weights are PINNED into VGPRs via opaque asm
// ("+v" inline-asm defs are not rematerializable). In R1-R5 the compiler
// re-loaded the const __restrict__ weight rows from cache EVERY step
// (VGPR_Count 84/120 < 128 floats proves it): 256 KB/CU/step ~ 3.9 TB/s/XCD,
// i.e. the L2 read-BW ceiling — the actual R1 bottleneck.
//
// Exchange protocol = R1 verbatim: fp32 4-byte agent-relaxed publishes; each
// thread polls its own 16 B slice; truncate-pack bf16 -> LDS (dbuf by t&1);
// ONE __syncthreads per step; in-wave butterfly + activations; lane 0
// publishes immediately. Guards bound all spins (fail wrong, never hang).
__global__ __launch_bounds__(512, 2)
void lstm_scan(const float* __restrict__ Wf, const float* __restrict__ Wi,
               const float* __restrict__ Wc, const float* __restrict__ Wo,
               const unsigned short* __restrict__ xproj,
               const float* __restrict__ Wy, const float* __restrict__ byv,
               float* __restrict__ hist,      // d_out hidden region [SEQ][HID]
               float* __restrict__ yout)      // d_out y region [SEQ][OUTW]
{
  const int b    = blockIdx.x;
  const int tid  = threadIdx.x;
  const int wv   = tid >> 6;
  const int lane = tid & 63;
  const int u    = b*8 + wv;

  __shared__ unsigned int h_lds[2][HID/2];  // packed bf16 pairs: word W = cols (2W,2W+1)
  __shared__ float As[16][68];              // epilogue staging
  __shared__ float Bs[16][68];

  // fp32 h-weights: wreg[r][kc*8+j] = W_{gate r}[u][8*lane + 512*kc + j]
  const float* const Wm[4] = {Wf, Wi, Wc, Wo};
  float wreg[4][32];
  #pragma unroll
  for (int r=0;r<4;r++){
    const float* rowp = Wm[r] + (size_t)u*3072;
    #pragma unroll
    for (int kc=0;kc<4;kc++){
      float4 f0 = *(const float4*)(rowp + 8*lane + 512*kc);
      float4 f1 = *(const float4*)(rowp + 8*lane + 512*kc + 4);
      wreg[r][kc*8+0]=f0.x; wreg[r][kc*8+1]=f0.y; wreg[r][kc*8+2]=f0.z; wreg[r][kc*8+3]=f0.w;
      wreg[r][kc*8+4]=f1.x; wreg[r][kc*8+5]=f1.y; wreg[r][kc*8+6]=f1.z; wreg[r][kc*8+7]=f1.w;
    }
  }
  // PIN: opaque defs -> allocator must keep all 128 weights live in VGPRs.
  #pragma unroll
  for (int r=0;r<4;r++)
    #pragma unroll
    for (int k=0;k<32;k++)
      asm volatile("" : "+v"(wreg[r][k]));

  float c = 0.0f;
  const unsigned short* xpp = xproj + (size_t)b*SEQ*32 + wv*4 + lane; // lane<4 valid

  for (int t=0; t<SEQ; t++){
    // x-projection (tiny, cached) — issue before the h spin
    float xp = (lane < 4) ? bf_lo((unsigned)xpp[(size_t)t*32]) : 0.0f;

    // ---- acquire h_{t-1}: R1 sentinel poll, verbatim ----
    uint2 pk;
    if (t == 0){
      pk.x = 0u; pk.y = 0u;                  // h_{-1} = 0 (bf16 zeros)
    } else {
      const unsigned long long* hp =
        (const unsigned long long*)(hist + (size_t)(t-1)*HID) + 2*tid;  // floats 4tid..4tid+3
      unsigned long long qa = __hip_atomic_load(hp,   __ATOMIC_RELAXED, __HIP_MEMORY_SCOPE_AGENT);
      unsigned long long qb = __hip_atomic_load(hp+1, __ATOMIC_RELAXED, __HIP_MEMORY_SCOPE_AGENT);
      int gd = 0;
      for(;;){
        bool ba = ((unsigned)qa==SENT) | ((unsigned)(qa>>32)==SENT);
        bool bb = ((unsigned)qb==SENT) | ((unsigned)(qb>>32)==SENT);
        if (!(ba|bb) || gd >= (1<<17)) break;   // guard: fail wrong, never hang
        if (ba) qa = __hip_atomic_load(hp,   __ATOMIC_RELAXED, __HIP_MEMORY_SCOPE_AGENT);
        if (bb) qb = __hip_atomic_load(hp+1, __ATOMIC_RELAXED, __HIP_MEMORY_SCOPE_AGENT);
        gd++;
      }
      unsigned a0=(unsigned)qa, a1=(unsigned)(qa>>32), a2=(unsigned)qb, a3=(unsigned)(qb>>32);
      pk.x = (a1 & 0xffff0000u) | (a0 >> 16);   // truncate-pack to bf16 pairs
      pk.y = (a3 & 0xffff0000u) | (a2 >> 16);
    }
    const int p = t & 1;
    *(uint2*)&h_lds[p][2*tid] = pk;
    __syncthreads();                          // the ONLY barrier per step

    // ---- dot: 4 gate rows x 32 cols/lane against PINNED register weights ----
    float acc[4] = {0.f,0.f,0.f,0.f};
    #pragma unroll
    for (int kc=0;kc<4;kc++){
      uint4 hw = *(const uint4*)&h_lds[p][4*lane + 256*kc];   // cols 8*lane+512*kc+0..7
      float hf[8];
      hf[0]=bf_lo(hw.x); hf[1]=bf_hi(hw.x); hf[2]=bf_lo(hw.y); hf[3]=bf_hi(hw.y);
      hf[4]=bf_lo(hw.z); hf[5]=bf_hi(hw.z); hf[6]=bf_lo(hw.w); hf[7]=bf_hi(hw.w);
      #pragma unroll
      for (int r=0;r<4;r++)
        #pragma unroll
        for (int j=0;j<8;j++)
          acc[r] = fmaf(wreg[r][kc*8+j], hf[j], acc[r]);
    }

    // ---- pair-folding butterfly: lane l ends with gate (l&3) fully reduced ----
    const int b0 = lane & 1;
    const int b1 = lane & 2;
    float x01 = b0 ? acc[1] : acc[0];
    float y01 = b0 ? acc[0] : acc[1];
    x01 += __shfl_xor(y01, 1);
    float x23 = b0 ? acc[3] : acc[2];
    float y23 = b0 ? acc[2] : acc[3];
    x23 += __shfl_xor(y23, 1);
    float xk = b1 ? x23 : x01;
    float yk = b1 ? x01 : x23;
    xk += __shfl_xor(yk, 2);
    xk += __shfl_xor(xk, 4);
    xk += __shfl_xor(xk, 8);
    xk += __shfl_xor(xk, 16);
    xk += __shfl_xor(xk, 32);

    // ---- activations in-wave ----
    float pre = xk + __shfl(xp, lane & 3);
    const bool ist = ((lane & 3) == 2);        // gate 2 = tanh, others sigmoid
    float px = ist ? fminf(15.0f, fmaxf(-15.0f, pre)) : pre;
    float e  = __expf(ist ? -2.0f*px : -px);
    float d  = 1.0f/(1.0f + e);
    float gv = ist ? (1.0f - e)*d : d;

    float f  = __shfl(gv, 0);
    float ii = __shfl(gv, 1);
    float cg = __shfl(gv, 2);
    float o  = __shfl(gv, 3);

    c = fmaf(f, c, ii*cg);
    float cx = fminf(15.0f, fmaxf(-15.0f, c));
    float e2 = __expf(-2.0f*cx);
    float h  = o * (1.0f - e2)/(1.0f + e2);

    // ---- publish immediately (fire-and-forget, self-validating) ----
    if (lane == 0)
      __hip_atomic_store(hist + (size_t)t*HID + u, h,
                         __ATOMIC_RELAXED, __HIP_MEMORY_SCOPE_AGENT);
  }

  // ================= epilogue: y[t][o] = W_y[o] @ h_t + b_y[o] =================
  // Row SEQ-1 complete => all rows complete (h_t required full h_{t-1}).
  {
    const unsigned long long* hp =
      (const unsigned long long*)(hist + (size_t)(SEQ-1)*HID) + 2*tid;
    unsigned long long qa = __hip_atomic_load(hp,   __ATOMIC_RELAXED, __HIP_MEMORY_SCOPE_AGENT);
    unsigned long long qb = __hip_atomic_load(hp+1, __ATOMIC_RELAXED, __HIP_MEMORY_SCOPE_AGENT);
    int gd = 0;
    for(;;){
      bool ba = ((unsigned)qa==SENT) | ((unsigned)(qa>>32)==SENT);
      bool bb = ((unsigned)qb==SENT) | ((unsigned)(qb>>32)==SENT);
      if (!(ba|bb) || gd >= (1<<17)) break;
      if (ba) qa = __hip_atomic_load(hp,   __ATOMIC_RELAXED, __HIP_MEMORY_SCOPE_AGENT);
      if (bb) qb = __hip_atomic_load(hp+1, __ATOMIC_RELAXED, __HIP_MEMORY_SCOPE_AGENT);
      gd++;
    }
  }
  __syncthreads();

  // one 64x64 tile per block; tid<256 computes (proven ygemm body), barriers uniform
  const int t0 = (b >> 3) * 64;
  const int o0 = (b & 7) * 64;
  const int tx = tid & 15, ty = (tid >> 4) & 15;
  const int lr = (tid & 255) >> 2;
  const int lk = (tid & 3) * 4;
  float yacc[4][4] = {};
  for (int k0 = 0; k0 < HID; k0 += 16){
    if (tid < 256){
      float4 av = *(const float4*)(hist + (size_t)(t0+lr)*HID + k0 + lk);
      float4 bv = *(const float4*)(Wy   + (size_t)(o0+lr)*HID + k0 + lk);
      As[lk+0][lr]=av.x; As[lk+1][lr]=av.y; As[lk+2][lr]=av.z; As[lk+3][lr]=av.w;
      Bs[lk+0][lr]=bv.x; Bs[lk+1][lr]=bv.y; Bs[lk+2][lr]=bv.z; Bs[lk+3][lr]=bv.w;
    }
    __syncthreads();
    if (tid < 256){
      #pragma unroll
      for (int kk=0;kk<16;kk++){
        float a[4], bb2[4];
        #pragma unroll
        for (int i=0;i<4;i++) a[i]   = As[kk][ty*4+i];
        #pragma unroll
        for (int j=0;j<4;j++) bb2[j] = Bs[kk][tx*4+j];
        #pragma unroll
        for (int i=0;i<4;i++)
          #pragma unroll
          for (int j=0;j<4;j++)
            yacc[i][j] = fmaf(a[i], bb2[j], yacc[i][j]);
      }
    }
    __syncthreads();
  }
  if (tid < 256){
    #pragma unroll
    for (int i=0;i<4;i++){
      int t = t0 + ty*4 + i;
      #pragma unroll
      for (int jj=0;jj<4;jj++){
        int o = o0 + tx*4 + jj;
        yout[(size_t)t*OUTW + o] = yacc[i][jj] + byv[o];
      }
    }
  }
}

extern "C" void kernel_launch(void* const* d_in, const int* in_sizes, int n_in,
                              void* d_out, int out_size, void* d_ws, size_t ws_size,
                              hipStream_t stream) {
  const float* X  = (const float*)d_in[0];
  const float* Wf = (const float*)d_in[1];
  const float* bf = (const float*)d_in[2];
  const float* Wi = (const float*)d_in[3];
  const float* bi = (const float*)d_in[4];
  const float* Wc = (const float*)d_in[5];
  const float* bc = (const float*)d_in[6];
  const float* Wo = (const float*)d_in[7];
  const float* bo = (const float*)d_in[8];
  const float* Wy = (const float*)d_in[9];
  const float* by = (const float*)d_in[10];

  float* yout = (float*)d_out;                       // [2048][512]
  float* hist = (float*)d_out + (size_t)SEQ*OUTW;    // [2048][2048]

  const size_t XPROJ_BYTES = (size_t)256*SEQ*32*sizeof(unsigned short); // 33,554,432
  if (ws_size < XPROJ_BYTES) return;   // clean failure instead of corruption

  unsigned short* xproj = (unsigned short*)d_ws;

  // sentinel-fill hist (16 MB); stream-ordered before the scan
  fill_hist<<<(SEQ*(size_t)HID/4)/256, 256, 0, stream>>>((uint4*)hist);

  dim3 gA(32, 128);
  xproj_gemm<<<gA, 256, 0, stream>>>(Wf,Wi,Wc,Wo, bf,bi,bc,bo, X, xproj);
  lstm_scan<<<256, 512, 0, stream>>>(Wf,Wi,Wc,Wo, xproj, Wy, by, hist, yout);
}